// Round 7
// baseline (205.310 us; speedup 1.0000x reference)
//
#include <hip/hip_runtime.h>
#include <hip/hip_bf16.h>
#include <stdint.h>

typedef __bf16 bf16_t;
typedef __bf16 bf16x8 __attribute__((ext_vector_type(8)));
typedef __bf16 bf16x4 __attribute__((ext_vector_type(4)));
typedef __bf16 bf16x2 __attribute__((ext_vector_type(2)));
typedef float floatx4 __attribute__((ext_vector_type(4)));

#define QSCALE 0.180336879f  /* 0.125 * log2(e) : fold score scale + exp2 domain into Q */

#if __has_builtin(__builtin_amdgcn_cvt_pk_bf16_f32)
#define HAS_PK_BF16 1
#endif

__device__ static inline void gll16(const void* g, void* l) {
    __builtin_amdgcn_global_load_lds((const __attribute__((address_space(1))) void*)g,
                                     (__attribute__((address_space(3))) void*)l, 16, 0, 0);
}

__device__ static inline bf16x8 pack8(const float* p) {
    bf16x8 o;
#ifdef HAS_PK_BF16
#pragma unroll
    for (int j = 0; j < 4; j++) {
        bf16x2 t2 = __builtin_amdgcn_cvt_pk_bf16_f32(p[2 * j], p[2 * j + 1]);
        o[2 * j] = t2[0]; o[2 * j + 1] = t2[1];
    }
#else
#pragma unroll
    for (int j = 0; j < 8; j++) o[j] = (bf16_t)p[j];
#endif
    return o;
}

// ---------------------------------------------------------------- fp32 -> bf16 (fused: inp, Wqkv, Wo)
__global__ __launch_bounds__(256) void cvt_all(const float* __restrict__ inp,
                                               const float* __restrict__ wqkv,
                                               const float* __restrict__ wo,
                                               bf16_t* __restrict__ o_inp,
                                               bf16_t* __restrict__ o_wqkv,
                                               bf16_t* __restrict__ o_wo) {
    int blk = blockIdx.x;
    const float* src;
    bf16_t* dst;
    if (blk < 4096)      { src = inp;  dst = o_inp; }
    else if (blk < 7168) { src = wqkv; dst = o_wqkv; blk -= 4096; }
    else                 { src = wo;   dst = o_wo;   blk -= 7168; }
    int i = blk * 256 + threadIdx.x;
    float4 v = ((const float4*)src)[i];
    float p[4] = {v.x, v.y, v.z, v.w};
    bf16x4 o;
#ifdef HAS_PK_BF16
    bf16x2 t0 = __builtin_amdgcn_cvt_pk_bf16_f32(p[0], p[1]);
    bf16x2 t1 = __builtin_amdgcn_cvt_pk_bf16_f32(p[2], p[3]);
    o[0] = t0[0]; o[1] = t0[1]; o[2] = t1[0]; o[3] = t1[1];
#else
    o[0] = (bf16_t)p[0]; o[1] = (bf16_t)p[1]; o[2] = (bf16_t)p[2]; o[3] = (bf16_t)p[3];
#endif
    ((bf16x4*)dst)[i] = o;
}

// ---------------------------------------------------------------- QKV GEMM (gll staging)
// vT columns are written t-PERMUTED within each 32-group: p = (t&~31) | q*8 | h*4 | r
// so attention's PV B-fragment read at quad*8 matches the in-register A-fragment order.
__global__ __launch_bounds__(256, 3)
void gemm_qkv(const bf16_t* __restrict__ A, const bf16_t* __restrict__ Bw,
              const float* __restrict__ bias,
              bf16_t* __restrict__ qk, bf16_t* __restrict__ vT) {
    constexpr int K = 1024;
    __shared__ bf16_t lA[128 * 32];
    __shared__ bf16_t lB[128 * 32];
    const int tid  = threadIdx.x;
    const int lane = tid & 63, wave = tid >> 6;
    const int quad = lane >> 4, l16 = lane & 15;
    const int wy = wave >> 1, wx = wave & 1;
    const int bm = blockIdx.y * 128, bn = blockIdx.x * 128;

    const int c0 = tid, c1 = tid + 256;
    const bf16_t* Ap0 = A + (size_t)(bm + (c0 >> 2)) * K + (c0 & 3) * 8;
    const bf16_t* Ap1 = A + (size_t)(bm + (c1 >> 2)) * K + (c1 & 3) * 8;
    const bf16_t* Bp0 = Bw + (size_t)(bn + (c0 >> 2)) * K + (c0 & 3) * 8;
    const bf16_t* Bp1 = Bw + (size_t)(bn + (c1 >> 2)) * K + (c1 & 3) * 8;
    bf16_t* dA0 = &lA[(wave * 64) * 8];
    bf16_t* dA1 = &lA[(256 + wave * 64) * 8];
    bf16_t* dB0 = &lB[(wave * 64) * 8];
    bf16_t* dB1 = &lB[(256 + wave * 64) * 8];

    floatx4 acc[4][4] = {};

    for (int kt = 0; kt < K; kt += 32) {
        __syncthreads();
        gll16(Ap0 + kt, dA0);
        gll16(Ap1 + kt, dA1);
        gll16(Bp0 + kt, dB0);
        gll16(Bp1 + kt, dB1);
        __syncthreads();
        bf16x8 af[4], bfr[4];
#pragma unroll
        for (int i = 0; i < 4; i++) {
            af[i]  = *(const bf16x8*)(lA + (wy * 64 + i * 16 + l16) * 32 + quad * 8);
            bfr[i] = *(const bf16x8*)(lB + (wx * 64 + i * 16 + l16) * 32 + quad * 8);
        }
#pragma unroll
        for (int i = 0; i < 4; i++)
#pragma unroll
            for (int j = 0; j < 4; j++)
                acc[i][j] = __builtin_amdgcn_mfma_f32_16x16x32_bf16(af[i], bfr[j], acc[i][j], 0, 0, 0);
    }

    const bool is_v = (bn >= 2048);
#pragma unroll
    for (int j = 0; j < 4; j++) {
        const int n = bn + wx * 64 + j * 16 + l16;
        const float bv = bias[n];
        const bool isq = (n < 1024);
#pragma unroll
        for (int i = 0; i < 4; i++) {
            const int mbase = bm + wy * 64 + i * 16 + quad * 4;
            if (!is_v) {
#pragma unroll
                for (int r = 0; r < 4; r++) {
                    float c = acc[i][j][r] + bv;
                    if (isq) c *= QSCALE;
                    qk[(size_t)(mbase + r) * 2048 + n] = (bf16_t)c;
                }
            } else {
                const int nn = n - 2048;             // h*64 + d
                const int b  = mbase >> 11;
                const int t  = mbase & 2047;         // 4-aligned
                const int vrow = b * 1024 + nn;      // (b*16+h)*64 + d
                const int pcol = (t & ~31) | (((t >> 2) & 3) << 3) | (((t >> 4) & 1) << 2);
                bf16x4 pack;
#pragma unroll
                for (int r = 0; r < 4; r++) pack[r] = (bf16_t)(acc[i][j][r] + bv);
                *(bf16x4*)(vT + (size_t)vrow * 2048 + pcol) = pack;
            }
        }
    }
}

// ---------------------------------------------------------------- flash attention (S^T, split-K, gll-staged K/V)
// Grid 1024 = 32 hl x 16 qt x 2 t-halves. Block = 4 waves x 32 q-rows.
// PV A-fragments built entirely in registers (t-permuted vT). No P LDS.
__global__ __launch_bounds__(256, 4)
void attn_kernel(const bf16_t* __restrict__ qk, const bf16_t* __restrict__ vT,
                 bf16_t* __restrict__ Opart, float* __restrict__ lpart) {
    __shared__ bf16_t Kbuf[2][64 * 64];   // [dbuf][ d-half(2) ][ t(64) ][ d(32) ]  (lane-linear)
    __shared__ bf16_t Vbuf[2][64 * 64];   // [dbuf][ t-half(2) ][ d(64) ][ p(32) ]
    const int tid  = threadIdx.x;
    const int lane = tid & 63, wave = tid >> 6;
    const int quad = lane >> 4, l16 = lane & 15;
    const int bid = blockIdx.x;
    const int s    = bid & 63;
    const int hl   = ((s & 7) << 2) | ((s >> 3) & 3);  // XCD-swizzle: 4 heads/XCD
    const int half = (s >> 5) & 1;
    const int qt   = bid >> 6;
    const int b = hl >> 4, h = hl & 15;
    const int kt0 = half * 1024;

    const bf16_t* Qbase = qk + (size_t)(b * 2048 + qt * 128 + wave * 32) * 2048 + h * 64;
    const bf16_t* Kbase = qk + (size_t)(b * 2048) * 2048 + 1024 + h * 64;
    const bf16_t* Vbase = vT + (size_t)(hl * 64) * 2048;

    const int srow = tid >> 2, sc8 = (tid & 3) * 8;
    const bf16_t* KgA = Kbase + (size_t)(kt0 + srow) * 2048 + sc8;   // d 0..31
    const bf16_t* KgB = KgA + 32;                                     // d 32..63
    const bf16_t* VgA = Vbase + (size_t)srow * 2048 + kt0 + sc8;     // t-half 0 (p-cols)
    const bf16_t* VgB = VgA + 32;                                     // t-half 1
    const int wbase = wave * 512;   // wave-uniform LDS dest; HW adds lane*16B

    bf16x8 qf[2][2];  // B-operand: n = q = l16, k = kc*32 + quad*8
#pragma unroll
    for (int rt = 0; rt < 2; rt++)
#pragma unroll
        for (int kc = 0; kc < 2; kc++)
            qf[rt][kc] = *(const bf16x8*)(Qbase + (size_t)(rt * 16 + l16) * 2048 + kc * 32 + quad * 8);

    floatx4 accO[2][4] = {};    // O[q=quad*4+r][d=ct*16+l16]
    float lacc[2] = {0.f, 0.f};

    gll16(KgA, &Kbuf[0][wbase]);
    gll16(KgB, &Kbuf[0][2048 + wbase]);
    gll16(VgA, &Vbuf[0][wbase]);
    gll16(VgB, &Vbuf[0][2048 + wbase]);

    for (int it = 0; it < 16; ++it) {
        const int cur = it & 1, nxt = cur ^ 1;
        __syncthreads();   // drains gll -> buf[cur] ready
        if (it < 15) {
            const size_t ko = (size_t)(it + 1) * 64 * 2048;
            const int    vo = (it + 1) * 64;
            gll16(KgA + ko, &Kbuf[nxt][wbase]);
            gll16(KgB + ko, &Kbuf[nxt][2048 + wbase]);
            gll16(VgA + vo, &Vbuf[nxt][wbase]);
            gll16(VgB + vo, &Vbuf[nxt][2048 + wbase]);
        }
        // S^T = K.Q^T : rows t (quad*4+r per nt-tile), cols q (l16)
        floatx4 st[2][4] = {};
#pragma unroll
        for (int nt = 0; nt < 4; nt++) {
            bf16x8 k0 = *(const bf16x8*)&Kbuf[cur][(nt * 16 + l16) * 32 + quad * 8];
            bf16x8 k1 = *(const bf16x8*)&Kbuf[cur][2048 + (nt * 16 + l16) * 32 + quad * 8];
            st[0][nt] = __builtin_amdgcn_mfma_f32_16x16x32_bf16(k0, qf[0][0], st[0][nt], 0, 0, 0);
            st[0][nt] = __builtin_amdgcn_mfma_f32_16x16x32_bf16(k1, qf[0][1], st[0][nt], 0, 0, 0);
            st[1][nt] = __builtin_amdgcn_mfma_f32_16x16x32_bf16(k0, qf[1][0], st[1][nt], 0, 0, 0);
            st[1][nt] = __builtin_amdgcn_mfma_f32_16x16x32_bf16(k1, qf[1][1], st[1][nt], 0, 0, 0);
        }
        // per t-half: V frags once; P frags built in-register (permuted t-order)
#pragma unroll
        for (int kc2 = 0; kc2 < 2; kc2++) {
            bf16x8 vf[4];
#pragma unroll
            for (int ct = 0; ct < 4; ct++)
                vf[ct] = *(const bf16x8*)&Vbuf[cur][kc2 * 2048 + (ct * 16 + l16) * 32 + quad * 8];
#pragma unroll
            for (int rt = 0; rt < 2; rt++) {
                float p[8];
                float ls = 0.f;
#pragma unroll
                for (int j = 0; j < 8; j++) {
                    p[j] = __builtin_amdgcn_exp2f(st[rt][kc2 * 2 + (j >> 2)][j & 3]);
                    ls += p[j];
                }
                lacc[rt] += ls;
                bf16x8 pf = pack8(p);
#pragma unroll
                for (int ct = 0; ct < 4; ct++)
                    accO[rt][ct] = __builtin_amdgcn_mfma_f32_16x16x32_bf16(pf, vf[ct], accO[rt][ct], 0, 0, 0);
            }
        }
    }

    // partial l
    float lsum[2];
#pragma unroll
    for (int rt = 0; rt < 2; rt++) {
        float l = lacc[rt];
        l += __shfl_xor(l, 16);
        l += __shfl_xor(l, 32);
        lsum[rt] = l;
    }
    // partial O with "faithful bug" permutation: dest row (hl&1)*2048 + t, col (hl>>1)*64 + d
    const int b2 = hl & 1;
    const int colb = hl >> 1;
    const int rowb = b2 * 2048 + qt * 128 + wave * 32;
    bf16_t* outb = Opart + (size_t)half * (4096 * 1024) + (size_t)rowb * 1024 + colb * 64;
#pragma unroll
    for (int rt = 0; rt < 2; rt++)
#pragma unroll
        for (int ct = 0; ct < 4; ct++)
#pragma unroll
            for (int r = 0; r < 4; r++)
                outb[(size_t)(rt * 16 + quad * 4 + r) * 1024 + ct * 16 + l16] = (bf16_t)(accO[rt][ct][r]);
    if (quad == 0) {
#pragma unroll
        for (int rt = 0; rt < 2; rt++)
            lpart[half * 65536 + (rowb + rt * 16 + l16) * 16 + colb] = lsum[rt];
    }
}

// ---------------------------------------------------------------- O GEMM with fused split-K combine
// A staged as (O0+O1)*inv_l; A-loads software-pipelined (issued after the 2nd barrier,
// consumed next iteration -> hidden behind the MFMA phase). Output bf16.
__global__ __launch_bounds__(256, 4)
void gemm_o(const bf16_t* __restrict__ Op, const float* __restrict__ lp,
            const bf16_t* __restrict__ Bw, bf16_t* __restrict__ out) {
    constexpr int K = 1024;
    __shared__ bf16_t lA[64 * 32];    // 4 KB
    __shared__ bf16_t lB[128 * 32];   // 8 KB
    const int tid  = threadIdx.x;
    const int lane = tid & 63, wave = tid >> 6;
    const int quad = lane >> 4, l16 = lane & 15;
    const int wy = wave >> 1, wx = wave & 1;   // wave tile: 32m x 64n
    const int bm = blockIdx.y * 64, bn = blockIdx.x * 128;

    const int ca = tid;                         // A: 64 rows x 4 chunks
    const int arow = bm + (ca >> 2);
    const int ak   = (ca & 3) * 8;
    const bf16_t* Ap0 = Op + (size_t)arow * 1024 + ak;
    const bf16_t* Ap1 = Ap0 + (size_t)4096 * 1024;
    const float*  lrow = lp + arow * 16;
    const int cb0 = tid, cb1 = tid + 256;       // B: 128 rows x 4 chunks
    const bf16_t* Bp0 = Bw + (size_t)(bn + (cb0 >> 2)) * K + (cb0 & 3) * 8;
    const bf16_t* Bp1 = Bw + (size_t)(bn + (cb1 >> 2)) * K + (cb1 & 3) * 8;
    bf16_t* dB0 = &lB[(wave * 64) * 8];
    bf16_t* dB1 = &lB[(256 + wave * 64) * 8];

    // prologue: load A chunks for kt=0
    bf16x8 a0 = *(const bf16x8*)(Ap0);
    bf16x8 a1 = *(const bf16x8*)(Ap1);

    floatx4 acc[2][4] = {};
    for (int kt = 0; kt < K; kt += 32) {
        // combine partials (a0/a1 were prefetched a full MFMA phase ago)
        const int cb = (kt + ak) >> 6;
        const float inv = 1.0f / (lrow[cb] + lrow[65536 + cb]);
        float p[8];
#pragma unroll
        for (int j = 0; j < 8; j++) p[j] = ((float)a0[j] + (float)a1[j]) * inv;
        bf16x8 av = pack8(p);
        __syncthreads();                    // prior frag reads done
        gll16(Bp0 + kt, dB0);
        gll16(Bp1 + kt, dB1);
        *(bf16x8*)&lA[ca * 8] = av;
        __syncthreads();                    // drains gll + LDS writes
        if (kt + 32 < K) {                  // prefetch next A AFTER the barrier
            a0 = *(const bf16x8*)(Ap0 + kt + 32);
            a1 = *(const bf16x8*)(Ap1 + kt + 32);
        }
        bf16x8 af[2], bfr[4];
#pragma unroll
        for (int i = 0; i < 2; i++)
            af[i] = *(const bf16x8*)(lA + (wy * 32 + i * 16 + l16) * 32 + quad * 8);
#pragma unroll
        for (int j = 0; j < 4; j++)
            bfr[j] = *(const bf16x8*)(lB + (wx * 64 + j * 16 + l16) * 32 + quad * 8);
#pragma unroll
        for (int i = 0; i < 2; i++)
#pragma unroll
            for (int j = 0; j < 4; j++)
                acc[i][j] = __builtin_amdgcn_mfma_f32_16x16x32_bf16(af[i], bfr[j], acc[i][j], 0, 0, 0);
    }
#pragma unroll
    for (int j = 0; j < 4; j++) {
        const int n = bn + wx * 64 + j * 16 + l16;
#pragma unroll
        for (int i = 0; i < 2; i++) {
            const int mbase = bm + wy * 32 + i * 16 + quad * 4;
#pragma unroll
            for (int r = 0; r < 4; r++)
                out[(size_t)(mbase + r) * 1024 + n] = (bf16_t)acc[i][j][r];
        }
    }
}

// ---------------------------------------------------------------- residual + LayerNorm (ao in bf16)
__global__ __launch_bounds__(256)
void ln_kernel(const float* __restrict__ inp, const bf16_t* __restrict__ ao,
               const float* __restrict__ gamma, const float* __restrict__ beta,
               float* __restrict__ out) {
    const int row = blockIdx.x, tid = threadIdx.x;
    const int wave = tid >> 6, lane = tid & 63;
    float4 a = ((const float4*)(inp + (size_t)row * 1024))[tid];
    bf16x4 c4 = ((const bf16x4*)(ao + (size_t)row * 1024))[tid];
    float x0 = a.x + (float)c4[0], x1 = a.y + (float)c4[1];
    float x2 = a.z + (float)c4[2], x3 = a.w + (float)c4[3];
    float s = x0 + x1 + x2 + x3;
    float sq = x0 * x0 + x1 * x1 + x2 * x2 + x3 * x3;
#pragma unroll
    for (int mm = 32; mm >= 1; mm >>= 1) {
        s += __shfl_xor(s, mm);
        sq += __shfl_xor(sq, mm);
    }
    __shared__ float rs[4], rq[4];
    if (lane == 0) { rs[wave] = s; rq[wave] = sq; }
    __syncthreads();
    s = rs[0] + rs[1] + rs[2] + rs[3];
    sq = rq[0] + rq[1] + rq[2] + rq[3];
    const float mu = s * (1.0f / 1024.0f);
    const float var = sq * (1.0f / 1024.0f) - mu * mu;
    const float rstd = rsqrtf(var + 1e-5f);
    float4 g = ((const float4*)gamma)[tid], bt = ((const float4*)beta)[tid];
    float4 o;
    o.x = (x0 - mu) * rstd * g.x + bt.x;
    o.y = (x1 - mu) * rstd * g.y + bt.y;
    o.z = (x2 - mu) * rstd * g.z + bt.z;
    o.w = (x3 - mu) * rstd * g.w + bt.w;
    ((float4*)(out + (size_t)row * 1024))[tid] = o;
}

// ---------------------------------------------------------------- launch
extern "C" void kernel_launch(void* const* d_in, const int* in_sizes, int n_in,
                              void* d_out, int out_size, void* d_ws, size_t ws_size,
                              hipStream_t stream) {
    const float* inp   = (const float*)d_in[0];
    const float* Wqkv  = (const float*)d_in[1];
    const float* bqkv  = (const float*)d_in[2];
    const float* Wo    = (const float*)d_in[3];
    const float* gamma = (const float*)d_in[4];
    const float* beta  = (const float*)d_in[5];
    float* out = (float*)d_out;

    // workspace layout (64 MB):
    //  0- 8 : inp_bf   (dead after gemm_qkv)  -> lpart overlay (512 KB, attn)
    //  8-14 : wqkv_bf  (dead after gemm_qkv)
    // 14-16 : wo_bf    (live until gemm_o)
    // 16-32 : qk_buf   (dead after attn)
    // 32-40 : vT_buf   (dead after attn)      -> ao_bf overlay (8 MB, gemm_o out)
    // 48-64 : opart    (2 x 8 MB, attn out, read by gemm_o)
    char* ws = (char*)d_ws;
    bf16_t* inp_bf  = (bf16_t*)(ws);
    bf16_t* wqkv_bf = (bf16_t*)(ws + (8u << 20));
    bf16_t* wo_bf   = (bf16_t*)(ws + (14u << 20));
    bf16_t* qk_buf  = (bf16_t*)(ws + (16u << 20));
    bf16_t* vT_buf  = (bf16_t*)(ws + (32u << 20));
    bf16_t* ao_bf   = (bf16_t*)(ws + (32u << 20));
    bf16_t* opart   = (bf16_t*)(ws + (48u << 20));
    float*  lpart   = (float*)(ws);

    cvt_all<<<8192, 256, 0, stream>>>(inp, Wqkv, Wo, inp_bf, wqkv_bf, wo_bf);
    gemm_qkv<<<dim3(24, 32), 256, 0, stream>>>(inp_bf, wqkv_bf, bqkv, qk_buf, vT_buf);
    attn_kernel<<<1024, 256, 0, stream>>>(qk_buf, vT_buf, opart, lpart);
    gemm_o<<<dim3(8, 64), 256, 0, stream>>>(opart, lpart, wo_bf, ao_bf);
    ln_kernel<<<4096, 256, 0, stream>>>(inp, ao_bf, gamma, beta, out);
}

// Round 8
// 201.963 us; speedup vs baseline: 1.0166x; 1.0166x over previous
//
#include <hip/hip_runtime.h>
#include <hip/hip_bf16.h>
#include <stdint.h>

typedef __bf16 bf16_t;
typedef __bf16 bf16x8 __attribute__((ext_vector_type(8)));
typedef __bf16 bf16x4 __attribute__((ext_vector_type(4)));
typedef __bf16 bf16x2 __attribute__((ext_vector_type(2)));
typedef float floatx4 __attribute__((ext_vector_type(4)));

#define QSCALE 0.180336879f  /* 0.125 * log2(e) : fold score scale + exp2 domain into Q */

#if __has_builtin(__builtin_amdgcn_cvt_pk_bf16_f32)
#define HAS_PK_BF16 1
#endif

__device__ static inline void gll16(const void* g, void* l) {
    __builtin_amdgcn_global_load_lds((const __attribute__((address_space(1))) void*)g,
                                     (__attribute__((address_space(3))) void*)l, 16, 0, 0);
}

__device__ static inline bf16x8 pack8(const float* p) {
    bf16x8 o;
#ifdef HAS_PK_BF16
#pragma unroll
    for (int j = 0; j < 4; j++) {
        bf16x2 t2 = __builtin_amdgcn_cvt_pk_bf16_f32(p[2 * j], p[2 * j + 1]);
        o[2 * j] = t2[0]; o[2 * j + 1] = t2[1];
    }
#else
#pragma unroll
    for (int j = 0; j < 8; j++) o[j] = (bf16_t)p[j];
#endif
    return o;
}

// ---------------------------------------------------------------- fp32 -> bf16 (fused: inp, Wqkv, Wo)
__global__ __launch_bounds__(256) void cvt_all(const float* __restrict__ inp,
                                               const float* __restrict__ wqkv,
                                               const float* __restrict__ wo,
                                               bf16_t* __restrict__ o_inp,
                                               bf16_t* __restrict__ o_wqkv,
                                               bf16_t* __restrict__ o_wo) {
    int blk = blockIdx.x;
    const float* src;
    bf16_t* dst;
    if (blk < 4096)      { src = inp;  dst = o_inp; }
    else if (blk < 7168) { src = wqkv; dst = o_wqkv; blk -= 4096; }
    else                 { src = wo;   dst = o_wo;   blk -= 7168; }
    int i = blk * 256 + threadIdx.x;
    float4 v = ((const float4*)src)[i];
    float p[4] = {v.x, v.y, v.z, v.w};
    bf16x4 o;
#ifdef HAS_PK_BF16
    bf16x2 t0 = __builtin_amdgcn_cvt_pk_bf16_f32(p[0], p[1]);
    bf16x2 t1 = __builtin_amdgcn_cvt_pk_bf16_f32(p[2], p[3]);
    o[0] = t0[0]; o[1] = t0[1]; o[2] = t1[0]; o[3] = t1[1];
#else
    o[0] = (bf16_t)p[0]; o[1] = (bf16_t)p[1]; o[2] = (bf16_t)p[2]; o[3] = (bf16_t)p[3];
#endif
    ((bf16x4*)dst)[i] = o;
}

// ---------------------------------------------------------------- QKV GEMM (double-buffered gll staging)
// K-loop: single barrier/iter; tile k+1 DMA issued right after the barrier and drained at
// the NEXT barrier -> full compute phase of overlap (the R5 attn restructure).
// vT columns are t-PERMUTED within each 32-group: p = (t&~31) | q*8 | h*4 | r.
__global__ __launch_bounds__(256, 3)
void gemm_qkv(const bf16_t* __restrict__ A, const bf16_t* __restrict__ Bw,
              const float* __restrict__ bias,
              bf16_t* __restrict__ qk, bf16_t* __restrict__ vT) {
    constexpr int K = 1024;
    __shared__ bf16_t lA[2][128 * 32];
    __shared__ bf16_t lB[2][128 * 32];
    const int tid  = threadIdx.x;
    const int lane = tid & 63, wave = tid >> 6;
    const int quad = lane >> 4, l16 = lane & 15;
    const int wy = wave >> 1, wx = wave & 1;
    const int bm = blockIdx.y * 128, bn = blockIdx.x * 128;

    const int c0 = tid, c1 = tid + 256;
    const bf16_t* Ap0 = A + (size_t)(bm + (c0 >> 2)) * K + (c0 & 3) * 8;
    const bf16_t* Ap1 = A + (size_t)(bm + (c1 >> 2)) * K + (c1 & 3) * 8;
    const bf16_t* Bp0 = Bw + (size_t)(bn + (c0 >> 2)) * K + (c0 & 3) * 8;
    const bf16_t* Bp1 = Bw + (size_t)(bn + (c1 >> 2)) * K + (c1 & 3) * 8;
    const int d0 = (wave * 64) * 8;          // wave-uniform dest (elems); HW adds lane*16B
    const int d1 = (256 + wave * 64) * 8;

    floatx4 acc[4][4] = {};

    // prologue: stage tile 0
    gll16(Ap0, &lA[0][d0]);
    gll16(Ap1, &lA[0][d1]);
    gll16(Bp0, &lB[0][d0]);
    gll16(Bp1, &lB[0][d1]);

    for (int it = 0; it < 32; ++it) {
        const int cur = it & 1, nxt = cur ^ 1;
        __syncthreads();                       // drains gll -> buf[cur] ready
        if (it < 31) {
            const int kt = (it + 1) * 32;
            gll16(Ap0 + kt, &lA[nxt][d0]);
            gll16(Ap1 + kt, &lA[nxt][d1]);
            gll16(Bp0 + kt, &lB[nxt][d0]);
            gll16(Bp1 + kt, &lB[nxt][d1]);
        }
        bf16x8 af[4], bfr[4];
#pragma unroll
        for (int i = 0; i < 4; i++) {
            af[i]  = *(const bf16x8*)(&lA[cur][(wy * 64 + i * 16 + l16) * 32 + quad * 8]);
            bfr[i] = *(const bf16x8*)(&lB[cur][(wx * 64 + i * 16 + l16) * 32 + quad * 8]);
        }
#pragma unroll
        for (int i = 0; i < 4; i++)
#pragma unroll
            for (int j = 0; j < 4; j++)
                acc[i][j] = __builtin_amdgcn_mfma_f32_16x16x32_bf16(af[i], bfr[j], acc[i][j], 0, 0, 0);
    }

    const bool is_v = (bn >= 2048);
#pragma unroll
    for (int j = 0; j < 4; j++) {
        const int n = bn + wx * 64 + j * 16 + l16;
        const float bv = bias[n];
        const bool isq = (n < 1024);
#pragma unroll
        for (int i = 0; i < 4; i++) {
            const int mbase = bm + wy * 64 + i * 16 + quad * 4;
            if (!is_v) {
#pragma unroll
                for (int r = 0; r < 4; r++) {
                    float c = acc[i][j][r] + bv;
                    if (isq) c *= QSCALE;
                    qk[(size_t)(mbase + r) * 2048 + n] = (bf16_t)c;
                }
            } else {
                const int nn = n - 2048;             // h*64 + d
                const int b  = mbase >> 11;
                const int t  = mbase & 2047;         // 4-aligned
                const int vrow = b * 1024 + nn;      // (b*16+h)*64 + d
                const int pcol = (t & ~31) | (((t >> 2) & 3) << 3) | (((t >> 4) & 1) << 2);
                bf16x4 pack;
#pragma unroll
                for (int r = 0; r < 4; r++) pack[r] = (bf16_t)(acc[i][j][r] + bv);
                *(bf16x4*)(vT + (size_t)vrow * 2048 + pcol) = pack;
            }
        }
    }
}

// ---------------------------------------------------------------- flash attention (S^T, split-K, gll-staged K/V)
// Grid 1024 = 32 hl x 16 qt x 2 t-halves. Block = 4 waves x 32 q-rows.
// PV A-fragments built entirely in registers (t-permuted vT). No P LDS.
__global__ __launch_bounds__(256, 4)
void attn_kernel(const bf16_t* __restrict__ qk, const bf16_t* __restrict__ vT,
                 bf16_t* __restrict__ Opart, float* __restrict__ lpart) {
    __shared__ bf16_t Kbuf[2][64 * 64];   // [dbuf][ d-half(2) ][ t(64) ][ d(32) ]  (lane-linear)
    __shared__ bf16_t Vbuf[2][64 * 64];   // [dbuf][ t-half(2) ][ d(64) ][ p(32) ]
    const int tid  = threadIdx.x;
    const int lane = tid & 63, wave = tid >> 6;
    const int quad = lane >> 4, l16 = lane & 15;
    const int bid = blockIdx.x;
    const int s    = bid & 63;
    const int hl   = ((s & 7) << 2) | ((s >> 3) & 3);  // XCD-swizzle: 4 heads/XCD
    const int half = (s >> 5) & 1;
    const int qt   = bid >> 6;
    const int b = hl >> 4, h = hl & 15;
    const int kt0 = half * 1024;

    const bf16_t* Qbase = qk + (size_t)(b * 2048 + qt * 128 + wave * 32) * 2048 + h * 64;
    const bf16_t* Kbase = qk + (size_t)(b * 2048) * 2048 + 1024 + h * 64;
    const bf16_t* Vbase = vT + (size_t)(hl * 64) * 2048;

    const int srow = tid >> 2, sc8 = (tid & 3) * 8;
    const bf16_t* KgA = Kbase + (size_t)(kt0 + srow) * 2048 + sc8;   // d 0..31
    const bf16_t* KgB = KgA + 32;                                     // d 32..63
    const bf16_t* VgA = Vbase + (size_t)srow * 2048 + kt0 + sc8;     // t-half 0 (p-cols)
    const bf16_t* VgB = VgA + 32;                                     // t-half 1
    const int wbase = wave * 512;   // wave-uniform LDS dest; HW adds lane*16B

    bf16x8 qf[2][2];  // B-operand: n = q = l16, k = kc*32 + quad*8
#pragma unroll
    for (int rt = 0; rt < 2; rt++)
#pragma unroll
        for (int kc = 0; kc < 2; kc++)
            qf[rt][kc] = *(const bf16x8*)(Qbase + (size_t)(rt * 16 + l16) * 2048 + kc * 32 + quad * 8);

    floatx4 accO[2][4] = {};    // O[q=quad*4+r][d=ct*16+l16]
    float lacc[2] = {0.f, 0.f};

    gll16(KgA, &Kbuf[0][wbase]);
    gll16(KgB, &Kbuf[0][2048 + wbase]);
    gll16(VgA, &Vbuf[0][wbase]);
    gll16(VgB, &Vbuf[0][2048 + wbase]);

    for (int it = 0; it < 16; ++it) {
        const int cur = it & 1, nxt = cur ^ 1;
        __syncthreads();   // drains gll -> buf[cur] ready
        if (it < 15) {
            const size_t ko = (size_t)(it + 1) * 64 * 2048;
            const int    vo = (it + 1) * 64;
            gll16(KgA + ko, &Kbuf[nxt][wbase]);
            gll16(KgB + ko, &Kbuf[nxt][2048 + wbase]);
            gll16(VgA + vo, &Vbuf[nxt][wbase]);
            gll16(VgB + vo, &Vbuf[nxt][2048 + wbase]);
        }
        // S^T = K.Q^T : rows t (quad*4+r per nt-tile), cols q (l16)
        floatx4 st[2][4] = {};
#pragma unroll
        for (int nt = 0; nt < 4; nt++) {
            bf16x8 k0 = *(const bf16x8*)&Kbuf[cur][(nt * 16 + l16) * 32 + quad * 8];
            bf16x8 k1 = *(const bf16x8*)&Kbuf[cur][2048 + (nt * 16 + l16) * 32 + quad * 8];
            st[0][nt] = __builtin_amdgcn_mfma_f32_16x16x32_bf16(k0, qf[0][0], st[0][nt], 0, 0, 0);
            st[0][nt] = __builtin_amdgcn_mfma_f32_16x16x32_bf16(k1, qf[0][1], st[0][nt], 0, 0, 0);
            st[1][nt] = __builtin_amdgcn_mfma_f32_16x16x32_bf16(k0, qf[1][0], st[1][nt], 0, 0, 0);
            st[1][nt] = __builtin_amdgcn_mfma_f32_16x16x32_bf16(k1, qf[1][1], st[1][nt], 0, 0, 0);
        }
        // per t-half: V frags once; P frags built in-register (permuted t-order)
#pragma unroll
        for (int kc2 = 0; kc2 < 2; kc2++) {
            bf16x8 vf[4];
#pragma unroll
            for (int ct = 0; ct < 4; ct++)
                vf[ct] = *(const bf16x8*)&Vbuf[cur][kc2 * 2048 + (ct * 16 + l16) * 32 + quad * 8];
#pragma unroll
            for (int rt = 0; rt < 2; rt++) {
                float p[8];
                float ls = 0.f;
#pragma unroll
                for (int j = 0; j < 8; j++) {
                    p[j] = __builtin_amdgcn_exp2f(st[rt][kc2 * 2 + (j >> 2)][j & 3]);
                    ls += p[j];
                }
                lacc[rt] += ls;
                bf16x8 pf = pack8(p);
#pragma unroll
                for (int ct = 0; ct < 4; ct++)
                    accO[rt][ct] = __builtin_amdgcn_mfma_f32_16x16x32_bf16(pf, vf[ct], accO[rt][ct], 0, 0, 0);
            }
        }
    }

    // partial l
    float lsum[2];
#pragma unroll
    for (int rt = 0; rt < 2; rt++) {
        float l = lacc[rt];
        l += __shfl_xor(l, 16);
        l += __shfl_xor(l, 32);
        lsum[rt] = l;
    }
    // partial O with "faithful bug" permutation: dest row (hl&1)*2048 + t, col (hl>>1)*64 + d
    const int b2 = hl & 1;
    const int colb = hl >> 1;
    const int rowb = b2 * 2048 + qt * 128 + wave * 32;
    bf16_t* outb = Opart + (size_t)half * (4096 * 1024) + (size_t)rowb * 1024 + colb * 64;
#pragma unroll
    for (int rt = 0; rt < 2; rt++)
#pragma unroll
        for (int ct = 0; ct < 4; ct++)
#pragma unroll
            for (int r = 0; r < 4; r++)
                outb[(size_t)(rt * 16 + quad * 4 + r) * 1024 + ct * 16 + l16] = (bf16_t)(accO[rt][ct][r]);
    if (quad == 0) {
#pragma unroll
        for (int rt = 0; rt < 2; rt++)
            lpart[half * 65536 + (rowb + rt * 16 + l16) * 16 + colb] = lsum[rt];
    }
}

// ---------------------------------------------------------------- O GEMM, double-buffered, fused split-K combine
// B via gll prefetch-after-barrier; A regs prefetched at iter i, combined+staged to lA[nxt]
// AFTER the MFMA phase (load latency hidden); single barrier per iter. Output bf16.
__global__ __launch_bounds__(256, 4)
void gemm_o(const bf16_t* __restrict__ Op, const float* __restrict__ lp,
            const bf16_t* __restrict__ Bw, bf16_t* __restrict__ out) {
    constexpr int K = 1024;
    __shared__ bf16_t lA[2][64 * 32];    // 2 x 4 KB
    __shared__ bf16_t lB[2][128 * 32];   // 2 x 8 KB
    const int tid  = threadIdx.x;
    const int lane = tid & 63, wave = tid >> 6;
    const int quad = lane >> 4, l16 = lane & 15;
    const int wy = wave >> 1, wx = wave & 1;   // wave tile: 32m x 64n
    const int bm = blockIdx.y * 64, bn = blockIdx.x * 128;

    const int ca = tid;                         // A: 64 rows x 4 chunks
    const int arow = bm + (ca >> 2);
    const int ak   = (ca & 3) * 8;
    const bf16_t* Ap0 = Op + (size_t)arow * 1024 + ak;
    const bf16_t* Ap1 = Ap0 + (size_t)4096 * 1024;
    const float*  lrow = lp + arow * 16;
    const int cb0 = tid, cb1 = tid + 256;       // B: 128 rows x 4 chunks
    const bf16_t* Bp0 = Bw + (size_t)(bn + (cb0 >> 2)) * K + (cb0 & 3) * 8;
    const bf16_t* Bp1 = Bw + (size_t)(bn + (cb1 >> 2)) * K + (cb1 & 3) * 8;
    const int d0 = (wave * 64) * 8;
    const int d1 = (256 + wave * 64) * 8;

    // prologue: stage tile 0 (A combine + B gll)
    gll16(Bp0, &lB[0][d0]);
    gll16(Bp1, &lB[0][d1]);
    {
        bf16x8 a0 = *(const bf16x8*)(Ap0);
        bf16x8 a1 = *(const bf16x8*)(Ap1);
        const float inv = 1.0f / (lrow[ak >> 6] + lrow[65536 + (ak >> 6)]);
        float p[8];
#pragma unroll
        for (int j = 0; j < 8; j++) p[j] = ((float)a0[j] + (float)a1[j]) * inv;
        *(bf16x8*)&lA[0][ca * 8] = pack8(p);
    }

    floatx4 acc[2][4] = {};
    for (int it = 0; it < 32; ++it) {
        const int cur = it & 1, nxt = cur ^ 1;
        __syncthreads();                    // drains gll + lA writes -> [cur] ready
        bf16x8 na0, na1;
        int kt1 = (it + 1) * 32;
        if (it < 31) {
            na0 = *(const bf16x8*)(Ap0 + kt1);
            na1 = *(const bf16x8*)(Ap1 + kt1);
            gll16(Bp0 + kt1, &lB[nxt][d0]);
            gll16(Bp1 + kt1, &lB[nxt][d1]);
        }
        bf16x8 af[2], bfr[4];
#pragma unroll
        for (int i = 0; i < 2; i++)
            af[i] = *(const bf16x8*)(&lA[cur][(wy * 32 + i * 16 + l16) * 32 + quad * 8]);
#pragma unroll
        for (int j = 0; j < 4; j++)
            bfr[j] = *(const bf16x8*)(&lB[cur][(wx * 64 + j * 16 + l16) * 32 + quad * 8]);
#pragma unroll
        for (int i = 0; i < 2; i++)
#pragma unroll
            for (int j = 0; j < 4; j++)
                acc[i][j] = __builtin_amdgcn_mfma_f32_16x16x32_bf16(af[i], bfr[j], acc[i][j], 0, 0, 0);
        if (it < 31) {                      // combine after MFMA phase (na latency hidden)
            const int cb = (kt1 + ak) >> 6;
            const float inv = 1.0f / (lrow[cb] + lrow[65536 + cb]);
            float p[8];
#pragma unroll
            for (int j = 0; j < 8; j++) p[j] = ((float)na0[j] + (float)na1[j]) * inv;
            *(bf16x8*)&lA[nxt][ca * 8] = pack8(p);
        }
    }
#pragma unroll
    for (int j = 0; j < 4; j++) {
        const int n = bn + wx * 64 + j * 16 + l16;
#pragma unroll
        for (int i = 0; i < 2; i++) {
            const int mbase = bm + wy * 32 + i * 16 + quad * 4;
#pragma unroll
            for (int r = 0; r < 4; r++)
                out[(size_t)(mbase + r) * 1024 + n] = (bf16_t)acc[i][j][r];
        }
    }
}

// ---------------------------------------------------------------- residual + LayerNorm (ao in bf16)
__global__ __launch_bounds__(256)
void ln_kernel(const float* __restrict__ inp, const bf16_t* __restrict__ ao,
               const float* __restrict__ gamma, const float* __restrict__ beta,
               float* __restrict__ out) {
    const int row = blockIdx.x, tid = threadIdx.x;
    const int wave = tid >> 6, lane = tid & 63;
    float4 a = ((const float4*)(inp + (size_t)row * 1024))[tid];
    bf16x4 c4 = ((const bf16x4*)(ao + (size_t)row * 1024))[tid];
    float x0 = a.x + (float)c4[0], x1 = a.y + (float)c4[1];
    float x2 = a.z + (float)c4[2], x3 = a.w + (float)c4[3];
    float s = x0 + x1 + x2 + x3;
    float sq = x0 * x0 + x1 * x1 + x2 * x2 + x3 * x3;
#pragma unroll
    for (int mm = 32; mm >= 1; mm >>= 1) {
        s += __shfl_xor(s, mm);
        sq += __shfl_xor(sq, mm);
    }
    __shared__ float rs[4], rq[4];
    if (lane == 0) { rs[wave] = s; rq[wave] = sq; }
    __syncthreads();
    s = rs[0] + rs[1] + rs[2] + rs[3];
    sq = rq[0] + rq[1] + rq[2] + rq[3];
    const float mu = s * (1.0f / 1024.0f);
    const float var = sq * (1.0f / 1024.0f) - mu * mu;
    const float rstd = rsqrtf(var + 1e-5f);
    float4 g = ((const float4*)gamma)[tid], bt = ((const float4*)beta)[tid];
    float4 o;
    o.x = (x0 - mu) * rstd * g.x + bt.x;
    o.y = (x1 - mu) * rstd * g.y + bt.y;
    o.z = (x2 - mu) * rstd * g.z + bt.z;
    o.w = (x3 - mu) * rstd * g.w + bt.w;
    ((float4*)(out + (size_t)row * 1024))[tid] = o;
}

// ---------------------------------------------------------------- launch
extern "C" void kernel_launch(void* const* d_in, const int* in_sizes, int n_in,
                              void* d_out, int out_size, void* d_ws, size_t ws_size,
                              hipStream_t stream) {
    const float* inp   = (const float*)d_in[0];
    const float* Wqkv  = (const float*)d_in[1];
    const float* bqkv  = (const float*)d_in[2];
    const float* Wo    = (const float*)d_in[3];
    const float* gamma = (const float*)d_in[4];
    const float* beta  = (const float*)d_in[5];
    float* out = (float*)d_out;

    // workspace layout (64 MB):
    //  0- 8 : inp_bf   (dead after gemm_qkv)  -> lpart overlay (512 KB, attn)
    //  8-14 : wqkv_bf  (dead after gemm_qkv)
    // 14-16 : wo_bf    (live until gemm_o)
    // 16-32 : qk_buf   (dead after attn)
    // 32-40 : vT_buf   (dead after attn)      -> ao_bf overlay (8 MB, gemm_o out)
    // 48-64 : opart    (2 x 8 MB, attn out, read by gemm_o)
    char* ws = (char*)d_ws;
    bf16_t* inp_bf  = (bf16_t*)(ws);
    bf16_t* wqkv_bf = (bf16_t*)(ws + (8u << 20));
    bf16_t* wo_bf   = (bf16_t*)(ws + (14u << 20));
    bf16_t* qk_buf  = (bf16_t*)(ws + (16u << 20));
    bf16_t* vT_buf  = (bf16_t*)(ws + (32u << 20));
    bf16_t* ao_bf   = (bf16_t*)(ws + (32u << 20));
    bf16_t* opart   = (bf16_t*)(ws + (48u << 20));
    float*  lpart   = (float*)(ws);

    cvt_all<<<8192, 256, 0, stream>>>(inp, Wqkv, Wo, inp_bf, wqkv_bf, wo_bf);
    gemm_qkv<<<dim3(24, 32), 256, 0, stream>>>(inp_bf, wqkv_bf, bqkv, qk_buf, vT_buf);
    attn_kernel<<<1024, 256, 0, stream>>>(qk_buf, vT_buf, opart, lpart);
    gemm_o<<<dim3(8, 64), 256, 0, stream>>>(opart, lpart, wo_bf, ao_bf);
    ln_kernel<<<4096, 256, 0, stream>>>(inp, ao_bf, gamma, beta, out);
}